// Round 5
// baseline (272.691 us; speedup 1.0000x reference)
//
#include <hip/hip_runtime.h>
#include <hip/hip_runtime_api.h>
#include <cstdint>
#include <cstddef>

#define B_    64
#define P_    24564
#define C_    81
#define NOBJ_ 16
#define SLICE_ 1536   // ceil(P_/16)

__device__ __forceinline__ float smooth_l1(float d){
  float ad = fabsf(d);
  return (ad < 1.0f) ? 0.5f * d * d : ad - 0.5f;
}

// ---------------- init: zero accumulators ----------------
__global__ void k_init(unsigned long long* packed, int* n_pos, int* total_pos,
                       float* accs, int* done){
  int i = blockIdx.x * blockDim.x + threadIdx.x;
  if (i < B_ * NOBJ_) packed[i] = 0ull;
  if (i < B_) n_pos[i] = 0;
  if (i < 3) accs[i] = 0.f;
  if (i == 0){ *total_pos = 0; *done = 0; }
}

// ---------------- phase 1: per-object best prior + per-prior best object ----
// packed[b][o] = (iou_bits << 32) | (0xFFFFFFFF - prior_idx)  (atomicMax;
// ties -> smallest prior = np.argmax first-wins).
// ppbest[b*P+p] = (iou_bits << 32) | obj  (per-prior argmax, first-wins via >).
__global__ __launch_bounds__(256) void k_match1(const float* __restrict__ boxes,
                                                const float* __restrict__ priors,
                                                unsigned long long* __restrict__ packed,
                                                unsigned long long* __restrict__ ppbest){
  const int b = blockIdx.x, slice = blockIdx.y, tid = threadIdx.x;
  __shared__ float sb[NOBJ_ * 4];
  __shared__ float sba[NOBJ_];
  if (tid < NOBJ_ * 4) sb[tid] = boxes[b * NOBJ_ * 4 + tid];
  __syncthreads();
  if (tid < NOBJ_) sba[tid] = (sb[tid*4+2] - sb[tid*4+0]) * (sb[tid*4+3] - sb[tid*4+1]);
  __syncthreads();

  float bv[NOBJ_]; int bi[NOBJ_];
  #pragma unroll
  for (int o = 0; o < NOBJ_; ++o){ bv[o] = -1.f; bi[o] = 0x7FFFFFFF; }

  const int p0 = slice * SLICE_;
  for (int k = 0; k < SLICE_ / 256; ++k){
    int p = p0 + k * 256 + tid;
    if (p < P_){
      float4 pr = reinterpret_cast<const float4*>(priors)[p];
      float px0 = pr.x - pr.z / 2.f, py0 = pr.y - pr.w / 2.f;
      float px1 = pr.x + pr.z / 2.f, py1 = pr.y + pr.w / 2.f;
      float pa  = (px1 - px0) * (py1 - py0);
      float mx = -1.f; int am = 0;
      #pragma unroll
      for (int o = 0; o < NOBJ_; ++o){
        float ix = fminf(sb[o*4+2], px1) - fmaxf(sb[o*4+0], px0);
        float iy = fminf(sb[o*4+3], py1) - fmaxf(sb[o*4+1], py0);
        ix = fmaxf(ix, 0.f); iy = fmaxf(iy, 0.f);
        float inter = ix * iy;
        float v = __fdividef(inter, sba[o] + pa - inter);
        if (v > bv[o] || (v == bv[o] && p < bi[o])){ bv[o] = v; bi[o] = p; }
        if (v > mx){ mx = v; am = o; }   // per-prior argmax, first-wins
      }
      ppbest[(size_t)b * P_ + p] =
          ((unsigned long long)__float_as_uint(mx) << 32) | (unsigned)am;
    }
  }

  const int lane = tid & 63, wid = tid >> 6;
  #pragma unroll
  for (int o = 0; o < NOBJ_; ++o){
    for (int off = 32; off; off >>= 1){
      float v2 = __shfl_down(bv[o], off);
      int   i2 = __shfl_down(bi[o], off);
      if (v2 > bv[o] || (v2 == bv[o] && i2 < bi[o])){ bv[o] = v2; bi[o] = i2; }
    }
  }
  __shared__ float rv[4][NOBJ_];
  __shared__ int   ri[4][NOBJ_];
  if (lane == 0){
    #pragma unroll
    for (int o = 0; o < NOBJ_; ++o){ rv[wid][o] = bv[o]; ri[wid][o] = bi[o]; }
  }
  __syncthreads();
  if (tid < NOBJ_){
    float v = rv[0][tid]; int i = ri[0][tid];
    #pragma unroll
    for (int w = 1; w < 4; ++w){
      float v2 = rv[w][tid]; int i2 = ri[w][tid];
      if (v2 > v || (v2 == v && i2 < i)){ v = v2; i = i2; }
    }
    if (v >= 0.f){
      unsigned long long pk = ((unsigned long long)__float_as_uint(v) << 32)
                            | (unsigned long long)(0xFFFFFFFFu - (unsigned)i);
      atomicMax(&packed[b * NOBJ_ + tid], pk);
    }
  }
}

// ---------------- phase 2 (light): labels + loc loss from stored ppbest ------
__global__ __launch_bounds__(256) void k_match2(const float* __restrict__ boxes,
                                                const int*   __restrict__ labels,
                                                const float* __restrict__ priors,
                                                const float* __restrict__ pred_locs,
                                                const unsigned long long* __restrict__ packed,
                                                const unsigned long long* __restrict__ ppbest,
                                                int* __restrict__ true_classes,
                                                int* __restrict__ n_pos,
                                                int* __restrict__ total_pos,
                                                float* __restrict__ accs){
  const int b = blockIdx.x, slice = blockIdx.y, tid = threadIdx.x;
  __shared__ float sb[NOBJ_ * 4];
  __shared__ int   slab[NOBJ_];
  __shared__ int   sppo[NOBJ_];
  if (tid < NOBJ_ * 4) sb[tid] = boxes[b * NOBJ_ * 4 + tid];
  if (tid < NOBJ_){
    slab[tid] = labels[b * NOBJ_ + tid];
    unsigned long long pk = packed[b * NOBJ_ + tid];
    sppo[tid] = (int)(0xFFFFFFFFu - (unsigned)(pk & 0xFFFFFFFFull));
  }
  __syncthreads();

  int cnt = 0; float sl1 = 0.f;
  const int p0 = slice * SLICE_;
  for (int k = 0; k < SLICE_ / 256; ++k){
    int p = p0 + k * 256 + tid;
    if (p < P_){
      unsigned long long e = ppbest[(size_t)b * P_ + p];
      float mx = __uint_as_float((unsigned)(e >> 32));
      int   am = (int)(e & 0xFFFFFFFFull);
      #pragma unroll
      for (int o = 0; o < NOBJ_; ++o){
        if (sppo[o] == p){ am = o; mx = 1.0f; }   // ascending -> last-write-wins
      }
      int lab = slab[am];
      if (mx < 0.5f) lab = 0;
      true_classes[(size_t)b * P_ + p] = lab;
      if (lab != 0){
        ++cnt;
        float4 pr = reinterpret_cast<const float4*>(priors)[p];
        float x0 = sb[am*4+0], y0 = sb[am*4+1], x1 = sb[am*4+2], y1 = sb[am*4+3];
        float cx = (x0 + x1) / 2.f, cy = (y0 + y1) / 2.f;
        float w_  = x1 - x0, h_ = y1 - y0;
        float g0 = (cx - pr.x) / (pr.z / 10.0f);
        float g1 = (cy - pr.y) / (pr.w / 10.0f);
        float g2 = logf(w_ / pr.z) * 5.0f;
        float g3 = logf(h_ / pr.w) * 5.0f;
        float4 pl = reinterpret_cast<const float4*>(pred_locs)[(size_t)b * P_ + p];
        sl1 += smooth_l1(pl.x - g0) + smooth_l1(pl.y - g1)
             + smooth_l1(pl.z - g2) + smooth_l1(pl.w - g3);
      }
    }
  }
  for (int off = 32; off; off >>= 1){
    cnt += __shfl_down(cnt, off);
    sl1 += __shfl_down(sl1, off);
  }
  __shared__ int   rc[4];
  __shared__ float rs[4];
  const int lane = tid & 63, wid = tid >> 6;
  if (lane == 0){ rc[wid] = cnt; rs[wid] = sl1; }
  __syncthreads();
  if (tid == 0){
    int c = 0; float s = 0.f;
    for (int w = 0; w < 4; ++w){ c += rc[w]; s += rs[w]; }
    atomicAdd(&n_pos[b], c);
    atomicAdd(total_pos, c);
    atomicAdd(&accs[0], s);
  }
}

// ---------------- CE: 1-wave persistent block, dbuf global_load_lds pipeline ----
#define TILE_F 2592   // 32*81 floats per tile = 10368 B = 648 float4

__device__ __forceinline__ void stage_tile(const float* gsrc, float* lds, int lane){
  const float4* s4 = reinterpret_cast<const float4*>(gsrc);
  #pragma unroll
  for (int k = 0; k < 10; ++k){
    __builtin_amdgcn_global_load_lds(
        (const __attribute__((address_space(1))) void*)(s4 + k * 64 + lane),
        (__attribute__((address_space(3))) void*)(lds + k * 256), 16, 0, 0);
  }
  if (lane < 8)
    __builtin_amdgcn_global_load_lds(
        (const __attribute__((address_space(1))) void*)(s4 + 640 + lane),
        (__attribute__((address_space(3))) void*)(lds + 2560), 16, 0, 0);
}

__device__ __forceinline__ float tile_compute(const float* lbuf, const int* stc, int t,
                                              int lane, size_t row0,
                                              float* __restrict__ ce_neg){
  const int r = lane & 31, h = lane >> 5;
  const int base = r * 81 + h * 41;
  float sum = 0.f;
  #pragma unroll
  for (int j = 0; j < 40; ++j) sum += __expf(lbuf[base + j]);
  if (!h) sum += __expf(lbuf[base + 40]);
  sum += __shfl_xor(sum, 32);
  float pos = 0.f;
  if (!h){
    int cls = stc[t * 32 + r];
    float ce = __logf(sum) - lbuf[r * 81 + cls];
    float neg;
    if (cls != 0){ pos = ce; neg = 0.f; }
    else         { neg = fmaxf(ce, 0.f); }
    ce_neg[row0 + (size_t)t * 32 + r] = neg;
  }
  return pos;
}

__global__ __launch_bounds__(64) void k_ce(const float* __restrict__ scores,
                                           const int*   __restrict__ tc,
                                           float* __restrict__ ce_neg,
                                           float* __restrict__ conf_pos){
  __shared__ float sM[2 * TILE_F];
  __shared__ int   stc[256];
  const int lane = threadIdx.x;
  const size_t row0 = (size_t)blockIdx.x * 256;

  reinterpret_cast<int4*>(stc)[lane] = reinterpret_cast<const int4*>(tc + row0)[lane];
  __syncthreads();

  const float* g0 = scores + row0 * (size_t)C_;
  stage_tile(g0, sM, lane);
  float posacc = 0.f;
  int buf = 0;
  for (int t = 0; t < 7; ++t){
    stage_tile(g0 + (size_t)(t + 1) * TILE_F, sM + (buf ^ 1) * TILE_F, lane);
    asm volatile("s_waitcnt vmcnt(11)" ::: "memory");
    posacc += tile_compute(sM + buf * TILE_F, stc, t, lane, row0, ce_neg);
    buf ^= 1;
  }
  asm volatile("s_waitcnt vmcnt(0)" ::: "memory");
  posacc += tile_compute(sM + buf * TILE_F, stc, 7, lane, row0, ce_neg);

  #pragma unroll
  for (int off = 16; off; off >>= 1) posacc += __shfl_down(posacc, off);
  if (lane == 0 && posacc != 0.f) atomicAdd(conf_pos, posacc);
}

// ---------------- per-image exact top-K sum + fused final combine -------------
// 512 threads. 64 lane-private histogram copies with +1 pad: hist[copy][bin],
// copy = tid&63, row stride 257 -> bank = (copy + bin) % 32: conflict-free,
// no same-address atomics within a wave. Suffix-scan select on wave 0.
__global__ __launch_bounds__(512) void k_topk(const float* __restrict__ ce_neg,
                                              const int*   __restrict__ n_pos,
                                              float* __restrict__ accs,
                                              const int* __restrict__ total_pos,
                                              int* __restrict__ done,
                                              float* __restrict__ out){
  const int b = blockIdx.x, tid = threadIdx.x;
  const float* v = ce_neg + (size_t)b * P_;
  const int K = 3 * n_pos[b];

  __shared__ int hist[64 * 257];
  __shared__ int histT[256];
  __shared__ unsigned s_prefix;
  __shared__ int s_rem;
  __shared__ float rsum[8];
  const int lane = tid & 63, wid = tid >> 6;
  const int copy = tid & 63;

  if (K > 0 && K >= P_){
    float s = 0.f;
    for (int p = tid; p < P_; p += 512) s += v[p];
    #pragma unroll
    for (int off = 32; off; off >>= 1) s += __shfl_down(s, off);
    if (lane == 0) rsum[wid] = s;
    __syncthreads();
    if (tid == 0){
      float t = 0.f;
      for (int w = 0; w < 8; ++w) t += rsum[w];
      atomicAdd(&accs[2], t);
    }
  } else if (K > 0){
    unsigned prefix = 0; int remaining = K;
    for (int shift = 24; shift >= 0; shift -= 8){
      for (int i = tid; i < 64 * 257; i += 512) hist[i] = 0;
      __syncthreads();
      unsigned hmask = (shift == 24) ? 0u : (0xFFFFFFFFu << (shift + 8));
      for (int p = tid; p < P_; p += 512){
        unsigned u = __float_as_uint(v[p]);
        if ((u & hmask) == prefix) atomicAdd(&hist[copy * 257 + ((u >> shift) & 255)], 1);
      }
      __syncthreads();
      if (tid < 256){
        int s = 0;
        #pragma unroll
        for (int w = 0; w < 64; ++w) s += hist[w * 257 + tid];
        histT[tid] = s;
      }
      __syncthreads();
      if (wid == 0){
        int a0 = histT[lane*4+0], a1 = histT[lane*4+1],
            a2 = histT[lane*4+2], a3 = histT[lane*4+3];
        int tl = a0 + a1 + a2 + a3;
        int run = tl;
        #pragma unroll
        for (int off = 1; off < 64; off <<= 1){
          int x = __shfl_down(run, off);
          if (lane + off < 64) run += x;
        }
        int E  = run - tl;       // elements in bins above this lane's 4 bins
        int s3 = E;
        int s2 = s3 + a3;
        int s1 = s2 + a2;
        int s0 = s1 + a1;
        if (s0 < remaining && s0 + a0 >= remaining){ s_prefix = prefix | ((unsigned)(lane*4+0) << shift); s_rem = remaining - s0; }
        if (s1 < remaining && s1 + a1 >= remaining){ s_prefix = prefix | ((unsigned)(lane*4+1) << shift); s_rem = remaining - s1; }
        if (s2 < remaining && s2 + a2 >= remaining){ s_prefix = prefix | ((unsigned)(lane*4+2) << shift); s_rem = remaining - s2; }
        if (s3 < remaining && s3 + a3 >= remaining){ s_prefix = prefix | ((unsigned)(lane*4+3) << shift); s_rem = remaining - s3; }
      }
      __syncthreads();
      prefix = s_prefix;
      remaining = s_rem;
      __syncthreads();
    }

    float tv = __uint_as_float(prefix);
    float sgt = 0.f;
    for (int p = tid; p < P_; p += 512){
      unsigned u = __float_as_uint(v[p]);
      if (u > prefix) sgt += v[p];
    }
    #pragma unroll
    for (int off = 32; off; off >>= 1) sgt += __shfl_down(sgt, off);
    if (lane == 0) rsum[wid] = sgt;
    __syncthreads();
    if (tid == 0){
      float s = 0.f;
      for (int w = 0; w < 8; ++w) s += rsum[w];
      atomicAdd(&accs[2], s + (float)remaining * tv);
    }
  }

  // fused final combine: last block to finish computes the output
  __syncthreads();
  if (tid == 0){
    __threadfence();
    int d = atomicAdd(done, 1);
    if (d == B_ - 1){
      float tp = (float)__hip_atomic_load(total_pos, __ATOMIC_RELAXED, __HIP_MEMORY_SCOPE_AGENT);
      float a0 = __hip_atomic_load(&accs[0], __ATOMIC_RELAXED, __HIP_MEMORY_SCOPE_AGENT);
      float a1 = __hip_atomic_load(&accs[1], __ATOMIC_RELAXED, __HIP_MEMORY_SCOPE_AGENT);
      float a2 = __hip_atomic_load(&accs[2], __ATOMIC_RELAXED, __HIP_MEMORY_SCOPE_AGENT);
      out[0] = (a2 + a1) / tp + a0 / (tp * 4.0f);
    }
  }
}

extern "C" void kernel_launch(void* const* d_in, const int* in_sizes, int n_in,
                              void* d_out, int out_size, void* d_ws, size_t ws_size,
                              hipStream_t stream){
  const float* pred_locs = (const float*)d_in[0];
  const float* scores    = (const float*)d_in[1];
  const float* boxes     = (const float*)d_in[2];
  const int*   labels    = (const int*)d_in[3];
  const float* priors    = (const float*)d_in[4];

  const size_t BP = (size_t)B_ * P_;
  char* w = (char*)d_ws;
  int*   true_classes = (int*)w;                               // BP int32
  float* ce_neg       = (float*)(w + BP * 4);                  // BP f32
  unsigned long long* ppbest = (unsigned long long*)(w + 2 * BP * 4);   // BP u64
  unsigned long long* packed = (unsigned long long*)(w + 2 * BP * 4 + BP * 8); // B*NOBJ u64
  char* w2 = w + 2 * BP * 4 + BP * 8 + (size_t)B_ * NOBJ_ * 8;
  int*   n_pos     = (int*)w2;                                 // B int
  int*   total_pos = n_pos + B_;                               // 1 int
  float* accs      = (float*)(total_pos + 1);                  // [sl1, conf_pos, hard]
  int*   done      = (int*)(accs + 3);                         // 1 int

  k_init<<<4, 256, 0, stream>>>(packed, n_pos, total_pos, accs, done);

  dim3 g1(B_, 16);
  k_match1<<<g1, 256, 0, stream>>>(boxes, priors, packed, ppbest);
  k_match2<<<g1, 256, 0, stream>>>(boxes, labels, priors, pred_locs, packed,
                                   ppbest, true_classes, n_pos, total_pos, accs);

  // 256 rows per 64-thread block; BP = 1,572,096 = 6141 * 256 exactly
  k_ce<<<(int)(BP / 256), 64, 0, stream>>>(scores, true_classes, ce_neg, &accs[1]);

  k_topk<<<B_, 512, 0, stream>>>(ce_neg, n_pos, accs, total_pos, done, (float*)d_out);
}

// Round 6
// 233.752 us; speedup vs baseline: 1.1666x; 1.1666x over previous
//
#include <hip/hip_runtime.h>
#include <cstdint>
#include <cstddef>

#define B_    64
#define P_    24564
#define C_    81
#define NOBJ_ 16
#define SLICE_ 1536   // ceil(P_/16)
#define NCEB_ 6141    // B_*P_/256

__device__ __forceinline__ float smooth_l1(float d){
  float ad = fabsf(d);
  return (ad < 1.0f) ? 0.5f * d * d : ad - 0.5f;
}

// ---------------- phase 1: per-(image,slice) per-object best prior ----------
// pob[(b*16+slice)*16+o] = (iou_bits<<32) | (0xFFFFFFFF - prior_idx)
// u64 max order == (max iou, then min prior idx) since iou >= 0.
// No atomics: each block owns its 16 slots.
__global__ __launch_bounds__(256) void k_match1(const float* __restrict__ boxes,
                                                const float* __restrict__ priors,
                                                unsigned long long* __restrict__ pob){
  const int b = blockIdx.x, slice = blockIdx.y, tid = threadIdx.x;
  __shared__ float sb[NOBJ_ * 4];
  __shared__ float sba[NOBJ_];
  if (tid < NOBJ_ * 4) sb[tid] = boxes[b * NOBJ_ * 4 + tid];
  __syncthreads();
  if (tid < NOBJ_) sba[tid] = (sb[tid*4+2] - sb[tid*4+0]) * (sb[tid*4+3] - sb[tid*4+1]);
  __syncthreads();

  float bv[NOBJ_]; int bi[NOBJ_];
  #pragma unroll
  for (int o = 0; o < NOBJ_; ++o){ bv[o] = -1.f; bi[o] = 0x7FFFFFFF; }

  const int p0 = slice * SLICE_;
  for (int k = 0; k < SLICE_ / 256; ++k){
    int p = p0 + k * 256 + tid;
    if (p < P_){
      float4 pr = reinterpret_cast<const float4*>(priors)[p];
      float px0 = pr.x - pr.z / 2.f, py0 = pr.y - pr.w / 2.f;
      float px1 = pr.x + pr.z / 2.f, py1 = pr.y + pr.w / 2.f;
      float pa  = (px1 - px0) * (py1 - py0);
      #pragma unroll
      for (int o = 0; o < NOBJ_; ++o){
        float ix = fminf(sb[o*4+2], px1) - fmaxf(sb[o*4+0], px0);
        float iy = fminf(sb[o*4+3], py1) - fmaxf(sb[o*4+1], py0);
        ix = fmaxf(ix, 0.f); iy = fmaxf(iy, 0.f);
        float inter = ix * iy;
        float v = __fdividef(inter, sba[o] + pa - inter);
        if (v > bv[o] || (v == bv[o] && p < bi[o])){ bv[o] = v; bi[o] = p; }
      }
    }
  }

  const int lane = tid & 63, wid = tid >> 6;
  #pragma unroll
  for (int o = 0; o < NOBJ_; ++o){
    for (int off = 32; off; off >>= 1){
      float v2 = __shfl_down(bv[o], off);
      int   i2 = __shfl_down(bi[o], off);
      if (v2 > bv[o] || (v2 == bv[o] && i2 < bi[o])){ bv[o] = v2; bi[o] = i2; }
    }
  }
  __shared__ float rv[4][NOBJ_];
  __shared__ int   ri[4][NOBJ_];
  if (lane == 0){
    #pragma unroll
    for (int o = 0; o < NOBJ_; ++o){ rv[wid][o] = bv[o]; ri[wid][o] = bi[o]; }
  }
  __syncthreads();
  if (tid < NOBJ_){
    float v = rv[0][tid]; int i = ri[0][tid];
    #pragma unroll
    for (int w = 1; w < 4; ++w){
      float v2 = rv[w][tid]; int i2 = ri[w][tid];
      if (v2 > v || (v2 == v && i2 < i)){ v = v2; i = i2; }
    }
    pob[(size_t)(b * 16 + slice) * NOBJ_ + tid] =
        ((unsigned long long)__float_as_uint(v) << 32)
      | (unsigned long long)(0xFFFFFFFFu - (unsigned)i);
  }
}

// ---------------- phase 2: reduce pob -> sppo; per-prior match; loc loss -----
// Writes per-(b,slice) partials npos_p/sl1_p (own slots, no atomics).
__global__ __launch_bounds__(256) void k_match2(const float* __restrict__ boxes,
                                                const int*   __restrict__ labels,
                                                const float* __restrict__ priors,
                                                const float* __restrict__ pred_locs,
                                                const unsigned long long* __restrict__ pob,
                                                int* __restrict__ true_classes,
                                                int* __restrict__ npos_p,
                                                float* __restrict__ sl1_p){
  const int b = blockIdx.x, slice = blockIdx.y, tid = threadIdx.x;
  __shared__ float sb[NOBJ_ * 4];
  __shared__ float sba[NOBJ_];
  __shared__ int   slab[NOBJ_];
  __shared__ int   sppo[NOBJ_];
  if (tid < NOBJ_ * 4) sb[tid] = boxes[b * NOBJ_ * 4 + tid];
  if (tid < NOBJ_) slab[tid] = labels[b * NOBJ_ + tid];
  __syncthreads();
  if (tid < NOBJ_){
    sba[tid] = (sb[tid*4+2] - sb[tid*4+0]) * (sb[tid*4+3] - sb[tid*4+1]);
    unsigned long long m = 0ull;
    #pragma unroll
    for (int s = 0; s < 16; ++s){
      unsigned long long e = pob[(size_t)(b * 16 + s) * NOBJ_ + tid];
      if (e > m) m = e;
    }
    sppo[tid] = (int)(0xFFFFFFFFu - (unsigned)(m & 0xFFFFFFFFull));
  }
  __syncthreads();

  int cnt = 0; float sl1 = 0.f;
  const int p0 = slice * SLICE_;
  for (int k = 0; k < SLICE_ / 256; ++k){
    int p = p0 + k * 256 + tid;
    if (p < P_){
      float4 pr = reinterpret_cast<const float4*>(priors)[p];
      float px0 = pr.x - pr.z / 2.f, py0 = pr.y - pr.w / 2.f;
      float px1 = pr.x + pr.z / 2.f, py1 = pr.y + pr.w / 2.f;
      float pa  = (px1 - px0) * (py1 - py0);
      float mx = -1.f; int am = 0;
      #pragma unroll
      for (int o = 0; o < NOBJ_; ++o){
        float ix = fminf(sb[o*4+2], px1) - fmaxf(sb[o*4+0], px0);
        float iy = fminf(sb[o*4+3], py1) - fmaxf(sb[o*4+1], py0);
        ix = fmaxf(ix, 0.f); iy = fmaxf(iy, 0.f);
        float inter = ix * iy;
        float v = __fdividef(inter, sba[o] + pa - inter);
        if (v > mx){ mx = v; am = o; }   // first-wins (strict >)
      }
      #pragma unroll
      for (int o = 0; o < NOBJ_; ++o){
        if (sppo[o] == p){ am = o; mx = 1.0f; }   // ascending o = last-write-wins
      }
      int lab = slab[am];
      if (mx < 0.5f) lab = 0;
      true_classes[(size_t)b * P_ + p] = lab;
      if (lab != 0){
        ++cnt;
        float x0 = sb[am*4+0], y0 = sb[am*4+1], x1 = sb[am*4+2], y1 = sb[am*4+3];
        float cx = (x0 + x1) / 2.f, cy = (y0 + y1) / 2.f;
        float w_  = x1 - x0, h_ = y1 - y0;
        float g0 = (cx - pr.x) / (pr.z / 10.0f);
        float g1 = (cy - pr.y) / (pr.w / 10.0f);
        float g2 = logf(w_ / pr.z) * 5.0f;
        float g3 = logf(h_ / pr.w) * 5.0f;
        float4 pl = reinterpret_cast<const float4*>(pred_locs)[(size_t)b * P_ + p];
        sl1 += smooth_l1(pl.x - g0) + smooth_l1(pl.y - g1)
             + smooth_l1(pl.z - g2) + smooth_l1(pl.w - g3);
      }
    }
  }
  for (int off = 32; off; off >>= 1){
    cnt += __shfl_down(cnt, off);
    sl1 += __shfl_down(sl1, off);
  }
  __shared__ int   rc[4];
  __shared__ float rs[4];
  const int lane = tid & 63, wid = tid >> 6;
  if (lane == 0){ rc[wid] = cnt; rs[wid] = sl1; }
  __syncthreads();
  if (tid == 0){
    int c = 0; float s = 0.f;
    for (int w = 0; w < 4; ++w){ c += rc[w]; s += rs[w]; }
    npos_p[b * 16 + slice] = c;
    sl1_p[b * 16 + slice]  = s;
  }
}

// ---------------- CE: 1-wave persistent block, dbuf global_load_lds pipeline ----
#define TILE_F 2592   // 32*81 floats per tile = 10368 B = 648 float4

__device__ __forceinline__ void stage_tile(const float* gsrc, float* lds, int lane){
  const float4* s4 = reinterpret_cast<const float4*>(gsrc);
  #pragma unroll
  for (int k = 0; k < 10; ++k){
    __builtin_amdgcn_global_load_lds(
        (const __attribute__((address_space(1))) void*)(s4 + k * 64 + lane),
        (__attribute__((address_space(3))) void*)(lds + k * 256), 16, 0, 0);
  }
  if (lane < 8)
    __builtin_amdgcn_global_load_lds(
        (const __attribute__((address_space(1))) void*)(s4 + 640 + lane),
        (__attribute__((address_space(3))) void*)(lds + 2560), 16, 0, 0);
}

__device__ __forceinline__ float tile_compute(const float* lbuf, const int* stc, int t,
                                              int lane, size_t row0,
                                              float* __restrict__ ce_neg){
  const int r = lane & 31, h = lane >> 5;
  const int base = r * 81 + h * 41;
  float sum = 0.f;
  #pragma unroll
  for (int j = 0; j < 40; ++j) sum += __expf(lbuf[base + j]);
  if (!h) sum += __expf(lbuf[base + 40]);
  sum += __shfl_xor(sum, 32);
  float pos = 0.f;
  if (!h){
    int cls = stc[t * 32 + r];
    float ce = __logf(sum) - lbuf[r * 81 + cls];
    float neg;
    if (cls != 0){ pos = ce; neg = 0.f; }
    else         { neg = fmaxf(ce, 0.f); }
    ce_neg[row0 + (size_t)t * 32 + r] = neg;
  }
  return pos;
}

__global__ __launch_bounds__(64) void k_ce(const float* __restrict__ scores,
                                           const int*   __restrict__ tc,
                                           float* __restrict__ ce_neg,
                                           float* __restrict__ cepart){
  __shared__ float sM[2 * TILE_F];
  __shared__ int   stc[256];
  const int lane = threadIdx.x;
  const size_t row0 = (size_t)blockIdx.x * 256;

  reinterpret_cast<int4*>(stc)[lane] = reinterpret_cast<const int4*>(tc + row0)[lane];
  __syncthreads();

  const float* g0 = scores + row0 * (size_t)C_;
  stage_tile(g0, sM, lane);
  float posacc = 0.f;
  int buf = 0;
  for (int t = 0; t < 7; ++t){
    stage_tile(g0 + (size_t)(t + 1) * TILE_F, sM + (buf ^ 1) * TILE_F, lane);
    asm volatile("s_waitcnt vmcnt(11)" ::: "memory");
    posacc += tile_compute(sM + buf * TILE_F, stc, t, lane, row0, ce_neg);
    buf ^= 1;
  }
  asm volatile("s_waitcnt vmcnt(0)" ::: "memory");
  posacc += tile_compute(sM + buf * TILE_F, stc, 7, lane, row0, ce_neg);

  #pragma unroll
  for (int off = 16; off; off >>= 1) posacc += __shfl_down(posacc, off);
  if (lane == 0) cepart[blockIdx.x] = posacc;   // own slot, no atomic
}

// ---------------- per-image exact top-K sum via radix select ----------------
// 512 threads; 32 histogram copies with +1 pad (conflict-free banks, at most
// rare 2-way same-address within a wave). Writes hard[b] (own slot).
__global__ __launch_bounds__(512) void k_topk(const float* __restrict__ ce_neg,
                                              const int*   __restrict__ npos_p,
                                              float* __restrict__ hard){
  const int b = blockIdx.x, tid = threadIdx.x;
  const float* v = ce_neg + (size_t)b * P_;

  __shared__ int sKs;
  if (tid == 0){
    int k = 0;
    #pragma unroll
    for (int s = 0; s < 16; ++s) k += npos_p[b * 16 + s];
    sKs = 3 * k;
  }
  __syncthreads();
  const int K = sKs;
  if (K <= 0){ if (tid == 0) hard[b] = 0.f; return; }

  __shared__ int hist[32 * 257];
  __shared__ int histT[256];
  __shared__ unsigned s_prefix;
  __shared__ int s_rem;
  __shared__ float rsum[8];
  const int lane = tid & 63, wid = tid >> 6;
  const int copy = tid & 31;

  if (K >= P_){
    float s = 0.f;
    for (int p = tid; p < P_; p += 512) s += v[p];
    #pragma unroll
    for (int off = 32; off; off >>= 1) s += __shfl_down(s, off);
    if (lane == 0) rsum[wid] = s;
    __syncthreads();
    if (tid == 0){
      float t = 0.f;
      for (int w = 0; w < 8; ++w) t += rsum[w];
      hard[b] = t;
    }
    return;
  }

  unsigned prefix = 0; int remaining = K;
  for (int shift = 24; shift >= 0; shift -= 8){
    for (int i = tid; i < 32 * 257; i += 512) hist[i] = 0;
    __syncthreads();
    unsigned hmask = (shift == 24) ? 0u : (0xFFFFFFFFu << (shift + 8));
    for (int p = tid; p < P_; p += 512){
      unsigned u = __float_as_uint(v[p]);
      if ((u & hmask) == prefix) atomicAdd(&hist[copy * 257 + ((u >> shift) & 255)], 1);
    }
    __syncthreads();
    if (tid < 256){
      int s = 0;
      #pragma unroll
      for (int w = 0; w < 32; ++w) s += hist[w * 257 + tid];
      histT[tid] = s;
    }
    __syncthreads();
    if (wid == 0){
      int a0 = histT[lane*4+0], a1 = histT[lane*4+1],
          a2 = histT[lane*4+2], a3 = histT[lane*4+3];
      int tl = a0 + a1 + a2 + a3;
      int run = tl;
      #pragma unroll
      for (int off = 1; off < 64; off <<= 1){
        int x = __shfl_down(run, off);
        if (lane + off < 64) run += x;
      }
      int E  = run - tl;       // elements in bins above this lane's 4 bins
      int s3 = E;
      int s2 = s3 + a3;
      int s1 = s2 + a2;
      int s0 = s1 + a1;
      if (s0 < remaining && s0 + a0 >= remaining){ s_prefix = prefix | ((unsigned)(lane*4+0) << shift); s_rem = remaining - s0; }
      if (s1 < remaining && s1 + a1 >= remaining){ s_prefix = prefix | ((unsigned)(lane*4+1) << shift); s_rem = remaining - s1; }
      if (s2 < remaining && s2 + a2 >= remaining){ s_prefix = prefix | ((unsigned)(lane*4+2) << shift); s_rem = remaining - s2; }
      if (s3 < remaining && s3 + a3 >= remaining){ s_prefix = prefix | ((unsigned)(lane*4+3) << shift); s_rem = remaining - s3; }
    }
    __syncthreads();
    prefix = s_prefix;
    remaining = s_rem;
    __syncthreads();
  }

  float tv = __uint_as_float(prefix);
  float sgt = 0.f;
  for (int p = tid; p < P_; p += 512){
    unsigned u = __float_as_uint(v[p]);
    if (u > prefix) sgt += v[p];
  }
  #pragma unroll
  for (int off = 32; off; off >>= 1) sgt += __shfl_down(sgt, off);
  if (lane == 0) rsum[wid] = sgt;
  __syncthreads();
  if (tid == 0){
    float s = 0.f;
    for (int w = 0; w < 8; ++w) s += rsum[w];
    hard[b] = s + (float)remaining * tv;
  }
}

// ---------------- final: tree-reduce all partials, write out -----------------
__global__ __launch_bounds__(1024) void k_final(const float* __restrict__ cepart,
                                                const float* __restrict__ sl1_p,
                                                const int*   __restrict__ npos_p,
                                                const float* __restrict__ hard,
                                                float* __restrict__ out){
  const int tid = threadIdx.x, lane = tid & 63, wid = tid >> 6;
  float cp = 0.f;
  for (int i = tid; i < NCEB_; i += 1024) cp += cepart[i];
  float sl = sl1_p[tid];          // exactly 1024 slots (64*16)
  int   np = npos_p[tid];
  float hd = (tid < B_) ? hard[tid] : 0.f;

  #pragma unroll
  for (int off = 32; off; off >>= 1){
    cp += __shfl_down(cp, off);
    sl += __shfl_down(sl, off);
    np += __shfl_down(np, off);
    hd += __shfl_down(hd, off);
  }
  __shared__ float rcp[16], rsl[16], rhd[16];
  __shared__ int   rnp[16];
  if (lane == 0){ rcp[wid] = cp; rsl[wid] = sl; rnp[wid] = np; rhd[wid] = hd; }
  __syncthreads();
  if (tid == 0){
    float tcp = 0.f, tsl = 0.f, thd = 0.f; int tnp = 0;
    for (int w = 0; w < 16; ++w){ tcp += rcp[w]; tsl += rsl[w]; tnp += rnp[w]; thd += rhd[w]; }
    float tp = (float)tnp;
    out[0] = (thd + tcp) / tp + tsl / (tp * 4.0f);
  }
}

extern "C" void kernel_launch(void* const* d_in, const int* in_sizes, int n_in,
                              void* d_out, int out_size, void* d_ws, size_t ws_size,
                              hipStream_t stream){
  const float* pred_locs = (const float*)d_in[0];
  const float* scores    = (const float*)d_in[1];
  const float* boxes     = (const float*)d_in[2];
  const int*   labels    = (const int*)d_in[3];
  const float* priors    = (const float*)d_in[4];

  const size_t BP = (size_t)B_ * P_;
  char* w = (char*)d_ws;
  int*   true_classes = (int*)w;                               // BP int32
  float* ce_neg       = (float*)(w + BP * 4);                  // BP f32
  char*  w2           = w + 2 * BP * 4;
  unsigned long long* pob = (unsigned long long*)w2;           // 64*16*16 u64 (128 KB)
  int*   npos_p = (int*)  (w2 + 16384 * 8);                    // 1024 int
  float* sl1_p  = (float*)(w2 + 16384 * 8 + 1024 * 4);         // 1024 f32
  float* cepart = (float*)(w2 + 16384 * 8 + 1024 * 8);         // 6141 f32
  float* hard   = cepart + NCEB_;                              // 64 f32

  dim3 g1(B_, 16);
  k_match1<<<g1, 256, 0, stream>>>(boxes, priors, pob);
  k_match2<<<g1, 256, 0, stream>>>(boxes, labels, priors, pred_locs, pob,
                                   true_classes, npos_p, sl1_p);

  // 256 rows per 64-thread block; BP = 1,572,096 = 6141 * 256 exactly
  k_ce<<<NCEB_, 64, 0, stream>>>(scores, true_classes, ce_neg, cepart);

  k_topk<<<B_, 512, 0, stream>>>(ce_neg, npos_p, hard);

  k_final<<<1, 1024, 0, stream>>>(cepart, sl1_p, npos_p, hard, (float*)d_out);
}

// Round 7
// 200.279 us; speedup vs baseline: 1.3616x; 1.1671x over previous
//
#include <hip/hip_runtime.h>
#include <cstdint>
#include <cstddef>

#define B_      64
#define P_      24564
#define C_      81
#define NOBJ_   16
#define SLICE_  1536     // ceil(P_/16) for k_fixup's per-slice loop
#define NCEB_   6141     // B_*P_/256 CE blocks
#define CHUNKS_ 96       // IoU chunks per image (256 priors each; last = 244)
#define NBLK_   6144     // B_*CHUNKS_  (grid of k_main)
#define TILE_F  2592     // 32*81 floats per CE tile = 10368 B = 648 float4

__device__ __forceinline__ float smooth_l1(float d){
  float ad = fabsf(d);
  return (ad < 1.0f) ? 0.5f * d * d : ad - 0.5f;
}

__device__ __forceinline__ void stage_tile(const float* gsrc, float* lds, int lane){
  const float4* s4 = reinterpret_cast<const float4*>(gsrc);
  #pragma unroll
  for (int k = 0; k < 10; ++k){
    __builtin_amdgcn_global_load_lds(
        (const __attribute__((address_space(1))) void*)(s4 + k * 64 + lane),
        (__attribute__((address_space(3))) void*)(lds + k * 256), 16, 0, 0);
  }
  if (lane < 8)
    __builtin_amdgcn_global_load_lds(
        (const __attribute__((address_space(1))) void*)(s4 + 640 + lane),
        (__attribute__((address_space(3))) void*)(lds + 2560), 16, 0, 0);
}

// ce0[row] = logsumexp(scores[row,:]) - scores[row,0]   (the CE of a
// background-labeled row; >= 0 up to rounding). No match dependency.
__device__ __forceinline__ void tile_compute(const float* lbuf, int t, int lane,
                                             size_t row0, float* __restrict__ ce0){
  const int r = lane & 31, h = lane >> 5;
  const int base = r * 81 + h * 41;   // h0: 41 elems, h1: 40 elems
  float sum = 0.f;
  #pragma unroll
  for (int j = 0; j < 40; ++j) sum += __expf(lbuf[base + j]);
  if (!h) sum += __expf(lbuf[base + 40]);
  sum += __shfl_xor(sum, 32);
  if (!h)
    ce0[row0 + (size_t)t * 32 + r] = __logf(sum) - lbuf[r * 81];
}

// ---------------- k_main: fused CE (LSE) + IoU matching argmaxes -------------
// Each of 6144 blocks (1 wave):
//  * IoU for one 256-prior chunk of one image: per-object best prior over the
//    chunk -> pob[blk][o]; per-prior best object -> ppbest[img*P+p].
//    This VALU work hides under the CE staging loads' HBM latency.
//  * CE for 256 rows (blocks 0..6140): 8 tiles x 32 rows, double-buffered
//    global_load_lds with counted s_waitcnt vmcnt(11).
__global__ __launch_bounds__(64) void k_main(const float* __restrict__ scores,
                                             const float* __restrict__ priors,
                                             const float* __restrict__ boxes,
                                             float* __restrict__ ce0,
                                             unsigned long long* __restrict__ ppbest,
                                             unsigned long long* __restrict__ pob){
  __shared__ float sM[2 * TILE_F];
  const int lane = threadIdx.x;
  const int blk  = blockIdx.x;

  const int img = blk / CHUNKS_;
  const int chk = blk - img * CHUNKS_;
  const int pr0 = chk * 256;
  const int nval = P_ - pr0;           // >= 244; only j==3 can be OOB

  // load this chunk's priors (lane owns priors pr0 + j*64 + lane)
  float4 prv[4]; bool pvd[4];
  #pragma unroll
  for (int j = 0; j < 4; ++j){
    int idx = j * 64 + lane;
    pvd[j] = idx < nval;
    prv[j] = reinterpret_cast<const float4*>(priors)[pr0 + (pvd[j] ? idx : 0)];
  }

  const bool ce_act = blk < NCEB_;
  const size_t row0 = (size_t)blk * 256;
  const float* g0 = scores + row0 * (size_t)C_;
  if (ce_act) stage_tile(g0, sM, lane);        // tile 0 in flight during IoU

  float px0[4], py0[4], px1[4], py1[4], pa[4];
  #pragma unroll
  for (int j = 0; j < 4; ++j){
    px0[j] = prv[j].x - prv[j].z * 0.5f;  py0[j] = prv[j].y - prv[j].w * 0.5f;
    px1[j] = prv[j].x + prv[j].z * 0.5f;  py1[j] = prv[j].y + prv[j].w * 0.5f;
    pa[j]  = (px1[j] - px0[j]) * (py1[j] - py0[j]);
  }
  float mx[4]; int am[4];
  #pragma unroll
  for (int j = 0; j < 4; ++j){ mx[j] = -1.f; am[j] = 0; }

  #pragma unroll
  for (int o = 0; o < NOBJ_; ++o){
    float4 bo = reinterpret_cast<const float4*>(boxes)[img * NOBJ_ + o]; // uniform
    float ba = (bo.z - bo.x) * (bo.w - bo.y);
    float bbv = -1.f; int bbi = 0x7FFFFFFF;
    #pragma unroll
    for (int j = 0; j < 4; ++j){
      float ix = fminf(bo.z, px1[j]) - fmaxf(bo.x, px0[j]);
      float iy = fminf(bo.w, py1[j]) - fmaxf(bo.y, py0[j]);
      ix = fmaxf(ix, 0.f); iy = fmaxf(iy, 0.f);
      float inter = ix * iy;
      float v = __fdividef(inter, ba + pa[j] - inter);
      if (!pvd[j]) v = -2.f;
      int p = pr0 + j * 64 + lane;
      if (v > bbv){ bbv = v; bbi = p; }          // j ascending => first-wins
      if (v > mx[j]){ mx[j] = v; am[j] = o; }    // o ascending => first-wins
    }
    #pragma unroll
    for (int off = 32; off; off >>= 1){
      float v2 = __shfl_down(bbv, off);
      int   i2 = __shfl_down(bbi, off);
      if (v2 > bbv || (v2 == bbv && i2 < bbi)){ bbv = v2; bbi = i2; }
    }
    if (lane == 0)
      pob[(size_t)blk * NOBJ_ + o] =
          ((unsigned long long)__float_as_uint(bbv) << 32)
        | (unsigned long long)(0xFFFFFFFFu - (unsigned)bbi);
  }
  #pragma unroll
  for (int j = 0; j < 4; ++j){
    if (pvd[j])
      ppbest[(size_t)img * P_ + pr0 + j * 64 + lane] =
          ((unsigned long long)__float_as_uint(mx[j]) << 32) | (unsigned)am[j];
  }

  if (!ce_act) return;

  stage_tile(g0 + TILE_F, sM + TILE_F, lane);   // tile 1 in flight
  int buf = 0;
  for (int t = 0; t < 6; ++t){
    asm volatile("s_waitcnt vmcnt(11)" ::: "memory");   // tile t ready; t+1 flying
    tile_compute(sM + buf * TILE_F, t, lane, row0, ce0);
    stage_tile(g0 + (size_t)(t + 2) * TILE_F, sM + buf * TILE_F, lane);
    buf ^= 1;
  }
  asm volatile("s_waitcnt vmcnt(11)" ::: "memory");
  tile_compute(sM + buf * TILE_F, 6, lane, row0, ce0);
  buf ^= 1;
  asm volatile("s_waitcnt vmcnt(0)" ::: "memory");
  tile_compute(sM + buf * TILE_F, 7, lane, row0, ce0);
}

// ---------------- k_fixup: forced matches, labels, loc loss, ce_neg ----------
// grid (B, 16) x 256. Pure streaming: reads ppbest + ce0, no IoU recompute.
__global__ __launch_bounds__(256) void k_fixup(const float* __restrict__ boxes,
                                               const int*   __restrict__ labels,
                                               const float* __restrict__ priors,
                                               const float* __restrict__ pred_locs,
                                               const float* __restrict__ scores,
                                               const unsigned long long* __restrict__ pob,
                                               const unsigned long long* __restrict__ ppbest,
                                               const float* __restrict__ ce0,
                                               float* __restrict__ ce_neg,
                                               int*   __restrict__ npos_p,
                                               float* __restrict__ sl1_p,
                                               float* __restrict__ cpos_p){
  const int b = blockIdx.x, slice = blockIdx.y, tid = threadIdx.x;
  __shared__ float sb[NOBJ_ * 4];
  __shared__ int   slab[NOBJ_];
  __shared__ int   sppo[NOBJ_];
  __shared__ unsigned long long pm[16][NOBJ_];
  if (tid < NOBJ_ * 4) sb[tid] = boxes[b * NOBJ_ * 4 + tid];
  if (tid < NOBJ_) slab[tid] = labels[b * NOBJ_ + tid];
  {   // reduce pob over 96 chunks: 16 groups x 6 chunks, then 16-way merge
    int o = tid & 15, g = tid >> 4;
    unsigned long long m = 0ull;
    for (int c = g * 6; c < g * 6 + 6; ++c){
      unsigned long long e = pob[(size_t)(b * CHUNKS_ + c) * NOBJ_ + o];
      if (e > m) m = e;
    }
    pm[g][o] = m;
  }
  __syncthreads();
  if (tid < NOBJ_){
    unsigned long long m = 0ull;
    #pragma unroll
    for (int g = 0; g < 16; ++g) if (pm[g][tid] > m) m = pm[g][tid];
    sppo[tid] = (int)(0xFFFFFFFFu - (unsigned)(m & 0xFFFFFFFFull));
  }
  __syncthreads();

  int cnt = 0; float sl1 = 0.f, cpos = 0.f;
  const int p0 = slice * SLICE_;
  for (int k = 0; k < SLICE_ / 256; ++k){
    int p = p0 + k * 256 + tid;
    if (p < P_){
      const size_t row = (size_t)b * P_ + p;
      unsigned long long e = ppbest[row];
      float mxv = __uint_as_float((unsigned)(e >> 32));
      int   am  = (int)(e & 0xFFFFFFFFull);
      #pragma unroll
      for (int o = 0; o < NOBJ_; ++o){
        if (sppo[o] == p){ am = o; mxv = 1.0f; }   // ascending o: last-write-wins
      }
      int lab = slab[am];
      if (mxv < 0.5f) lab = 0;
      float c0 = ce0[row];
      float negv;
      if (lab != 0){
        ++cnt; negv = 0.f;
        float4 pr = reinterpret_cast<const float4*>(priors)[p];
        float x0 = sb[am*4+0], y0 = sb[am*4+1], x1 = sb[am*4+2], y1 = sb[am*4+3];
        float cx = (x0 + x1) / 2.f, cy = (y0 + y1) / 2.f;
        float w_ = x1 - x0, h_ = y1 - y0;
        float g0 = (cx - pr.x) / (pr.z / 10.0f);
        float g1 = (cy - pr.y) / (pr.w / 10.0f);
        float g2 = logf(w_ / pr.z) * 5.0f;
        float g3 = logf(h_ / pr.w) * 5.0f;
        float4 pl = reinterpret_cast<const float4*>(pred_locs)[row];
        sl1 += smooth_l1(pl.x - g0) + smooth_l1(pl.y - g1)
             + smooth_l1(pl.z - g2) + smooth_l1(pl.w - g3);
        const float* srow = scores + row * (size_t)C_;
        cpos += c0 + srow[0] - srow[lab];   // lse - s_t
      } else {
        negv = fmaxf(c0, 0.f);
      }
      ce_neg[row] = negv;
    }
  }
  for (int off = 32; off; off >>= 1){
    cnt  += __shfl_down(cnt, off);
    sl1  += __shfl_down(sl1, off);
    cpos += __shfl_down(cpos, off);
  }
  __shared__ int   rc[4];
  __shared__ float rs[4], rp[4];
  const int lane = tid & 63, wid = tid >> 6;
  if (lane == 0){ rc[wid] = cnt; rs[wid] = sl1; rp[wid] = cpos; }
  __syncthreads();
  if (tid == 0){
    int c = 0; float s = 0.f, q = 0.f;
    for (int w = 0; w < 4; ++w){ c += rc[w]; s += rs[w]; q += rp[w]; }
    npos_p[b * 16 + slice] = c;
    sl1_p[b * 16 + slice]  = s;
    cpos_p[b * 16 + slice] = q;
  }
}

// ---------------- per-image exact top-K sum via radix select ----------------
__global__ __launch_bounds__(512) void k_topk(const float* __restrict__ ce_neg,
                                              const int*   __restrict__ npos_p,
                                              float* __restrict__ hard){
  const int b = blockIdx.x, tid = threadIdx.x;
  const float* v = ce_neg + (size_t)b * P_;

  __shared__ int sKs;
  if (tid == 0){
    int k = 0;
    #pragma unroll
    for (int s = 0; s < 16; ++s) k += npos_p[b * 16 + s];
    sKs = 3 * k;
  }
  __syncthreads();
  const int K = sKs;
  if (K <= 0){ if (tid == 0) hard[b] = 0.f; return; }

  __shared__ int hist[32 * 257];
  __shared__ int histT[256];
  __shared__ unsigned s_prefix;
  __shared__ int s_rem;
  __shared__ float rsum[8];
  const int lane = tid & 63, wid = tid >> 6;
  const int copy = tid & 31;

  if (K >= P_){
    float s = 0.f;
    for (int p = tid; p < P_; p += 512) s += v[p];
    #pragma unroll
    for (int off = 32; off; off >>= 1) s += __shfl_down(s, off);
    if (lane == 0) rsum[wid] = s;
    __syncthreads();
    if (tid == 0){
      float t = 0.f;
      for (int w = 0; w < 8; ++w) t += rsum[w];
      hard[b] = t;
    }
    return;
  }

  unsigned prefix = 0; int remaining = K;
  for (int shift = 24; shift >= 0; shift -= 8){
    for (int i = tid; i < 32 * 257; i += 512) hist[i] = 0;
    __syncthreads();
    unsigned hmask = (shift == 24) ? 0u : (0xFFFFFFFFu << (shift + 8));
    for (int p = tid; p < P_; p += 512){
      unsigned u = __float_as_uint(v[p]);
      if ((u & hmask) == prefix) atomicAdd(&hist[copy * 257 + ((u >> shift) & 255)], 1);
    }
    __syncthreads();
    if (tid < 256){
      int s = 0;
      #pragma unroll
      for (int w = 0; w < 32; ++w) s += hist[w * 257 + tid];
      histT[tid] = s;
    }
    __syncthreads();
    if (wid == 0){
      int a0 = histT[lane*4+0], a1 = histT[lane*4+1],
          a2 = histT[lane*4+2], a3 = histT[lane*4+3];
      int tl = a0 + a1 + a2 + a3;
      int run = tl;
      #pragma unroll
      for (int off = 1; off < 64; off <<= 1){
        int x = __shfl_down(run, off);
        if (lane + off < 64) run += x;
      }
      int E  = run - tl;   // elements in bins above this lane's 4 bins
      int s3 = E;
      int s2 = s3 + a3;
      int s1 = s2 + a2;
      int s0 = s1 + a1;
      if (s0 < remaining && s0 + a0 >= remaining){ s_prefix = prefix | ((unsigned)(lane*4+0) << shift); s_rem = remaining - s0; }
      if (s1 < remaining && s1 + a1 >= remaining){ s_prefix = prefix | ((unsigned)(lane*4+1) << shift); s_rem = remaining - s1; }
      if (s2 < remaining && s2 + a2 >= remaining){ s_prefix = prefix | ((unsigned)(lane*4+2) << shift); s_rem = remaining - s2; }
      if (s3 < remaining && s3 + a3 >= remaining){ s_prefix = prefix | ((unsigned)(lane*4+3) << shift); s_rem = remaining - s3; }
    }
    __syncthreads();
    prefix = s_prefix;
    remaining = s_rem;
    __syncthreads();
  }

  float tv = __uint_as_float(prefix);
  float sgt = 0.f;
  for (int p = tid; p < P_; p += 512){
    unsigned u = __float_as_uint(v[p]);
    if (u > prefix) sgt += v[p];
  }
  #pragma unroll
  for (int off = 32; off; off >>= 1) sgt += __shfl_down(sgt, off);
  if (lane == 0) rsum[wid] = sgt;
  __syncthreads();
  if (tid == 0){
    float s = 0.f;
    for (int w = 0; w < 8; ++w) s += rsum[w];
    hard[b] = s + (float)remaining * tv;
  }
}

// ---------------- final: tree-reduce all partials, write out -----------------
__global__ __launch_bounds__(1024) void k_final(const float* __restrict__ cpos_p,
                                                const float* __restrict__ sl1_p,
                                                const int*   __restrict__ npos_p,
                                                const float* __restrict__ hard,
                                                float* __restrict__ out){
  const int tid = threadIdx.x, lane = tid & 63, wid = tid >> 6;
  float cp = cpos_p[tid];
  float sl = sl1_p[tid];
  int   np = npos_p[tid];
  float hd = (tid < B_) ? hard[tid] : 0.f;

  #pragma unroll
  for (int off = 32; off; off >>= 1){
    cp += __shfl_down(cp, off);
    sl += __shfl_down(sl, off);
    np += __shfl_down(np, off);
    hd += __shfl_down(hd, off);
  }
  __shared__ float rcp[16], rsl[16], rhd[16];
  __shared__ int   rnp[16];
  if (lane == 0){ rcp[wid] = cp; rsl[wid] = sl; rnp[wid] = np; rhd[wid] = hd; }
  __syncthreads();
  if (tid == 0){
    float tcp = 0.f, tsl = 0.f, thd = 0.f; int tnp = 0;
    for (int w = 0; w < 16; ++w){ tcp += rcp[w]; tsl += rsl[w]; tnp += rnp[w]; thd += rhd[w]; }
    float tp = (float)tnp;
    out[0] = (thd + tcp) / tp + tsl / (tp * 4.0f);
  }
}

extern "C" void kernel_launch(void* const* d_in, const int* in_sizes, int n_in,
                              void* d_out, int out_size, void* d_ws, size_t ws_size,
                              hipStream_t stream){
  const float* pred_locs = (const float*)d_in[0];
  const float* scores    = (const float*)d_in[1];
  const float* boxes     = (const float*)d_in[2];
  const int*   labels    = (const int*)d_in[3];
  const float* priors    = (const float*)d_in[4];

  const size_t BP = (size_t)B_ * P_;
  char* w = (char*)d_ws;
  float* ce_neg = (float*)w;                                    // BP f32
  float* ce0    = (float*)(w + BP * 4);                         // BP f32
  unsigned long long* ppbest = (unsigned long long*)(w + 2 * BP * 4);      // BP u64
  unsigned long long* pob    = (unsigned long long*)(w + 2 * BP * 4 + BP * 8); // NBLK_*16 u64
  char*  w2 = w + 2 * BP * 4 + BP * 8 + (size_t)NBLK_ * NOBJ_ * 8;
  int*   npos_p = (int*)  w2;                                   // 1024
  float* sl1_p  = (float*)(w2 + 1024 * 4);                      // 1024
  float* cpos_p = (float*)(w2 + 1024 * 8);                      // 1024
  float* hard   = (float*)(w2 + 1024 * 12);                     // 64

  k_main<<<NBLK_, 64, 0, stream>>>(scores, priors, boxes, ce0, ppbest, pob);

  dim3 g2(B_, 16);
  k_fixup<<<g2, 256, 0, stream>>>(boxes, labels, priors, pred_locs, scores,
                                  pob, ppbest, ce0, ce_neg, npos_p, sl1_p, cpos_p);

  k_topk<<<B_, 512, 0, stream>>>(ce_neg, npos_p, hard);

  k_final<<<1, 1024, 0, stream>>>(cpos_p, sl1_p, npos_p, hard, (float*)d_out);
}

// Round 9
// 182.602 us; speedup vs baseline: 1.4934x; 1.0968x over previous
//
#include <hip/hip_runtime.h>
#include <cstdint>
#include <cstddef>

#define B_      64
#define P_      24564
#define C_      81
#define NOBJ_   16
#define CHUNKS_ 96       // 256-prior chunks per image (last chunk: 244 valid)
#define NBLK_   6144     // B_*CHUNKS_
#define TILE_F  1296     // 16 rows * 81 floats
#define TILE_F4 324      // float4s per tile (5 full-wave gload_lds + 4 lanes)

typedef unsigned long long u64;

__device__ __forceinline__ float smooth_l1(float d){
  float ad = fabsf(d);
  return (ad < 1.0f) ? 0.5f * d * d : ad - 0.5f;
}

// identical arithmetic used by BOTH kernels (k_tail must reproduce k_main's
// per-prior argmax decisions; 1-ulp divergence is benign but avoid it anyway)
__device__ __forceinline__ float iou_pb(float bx0, float by0, float bx1, float by1,
                                        float ba, float px0, float py0,
                                        float px1, float py1, float pa){
  float ix = fminf(bx1, px1) - fmaxf(bx0, px0);
  float iy = fminf(by1, py1) - fmaxf(by0, py0);
  ix = fmaxf(ix, 0.f); iy = fmaxf(iy, 0.f);
  float inter = ix * iy;
  return __fdividef(inter, ba + pa - inter);
}

__device__ __forceinline__ float sl1_row4(const float* sbox, int am, float4 pr, float4 pl){
  float x0 = sbox[am*4+0], y0 = sbox[am*4+1], x1 = sbox[am*4+2], y1 = sbox[am*4+3];
  float cx = (x0 + x1) / 2.f, cy = (y0 + y1) / 2.f;
  float w_ = x1 - x0, h_ = y1 - y0;
  float g0 = (cx - pr.x) / (pr.z / 10.0f);
  float g1 = (cy - pr.y) / (pr.w / 10.0f);
  float g2 = logf(w_ / pr.z) * 5.0f;
  float g3 = logf(h_ / pr.w) * 5.0f;
  return smooth_l1(pl.x - g0) + smooth_l1(pl.y - g1)
       + smooth_l1(pl.z - g2) + smooth_l1(pl.w - g3);
}

// ---------------- k_main: per-chunk IoU + CE over the SAME 256 rows ----------
// grid (96, 64) x 64 threads. Block (chk, img) owns priors/rows
// [pr0, pr0+256) of image img. Writes ce_neg, per-chunk partials, pob.
__global__ __launch_bounds__(64) void k_main(const float* __restrict__ scores,
                                             const float* __restrict__ priors,
                                             const float* __restrict__ boxes,
                                             const int*   __restrict__ labels,
                                             const float* __restrict__ pred_locs,
                                             float* __restrict__ ce_neg,
                                             u64*   __restrict__ pob,
                                             int*   __restrict__ npos_c,
                                             float* __restrict__ sl1_c,
                                             float* __restrict__ cpos_c,
                                             int*   __restrict__ done){
  __shared__ float sM[2 * TILE_F];
  __shared__ float lmx[256];
  __shared__ int   lam[256];
  __shared__ float sbox[NOBJ_ * 4];
  __shared__ int   slab[NOBJ_];
  const int lane = threadIdx.x;
  const int chk = blockIdx.x, img = blockIdx.y;
  const int blkid = img * CHUNKS_ + chk;
  if (blkid == 0 && lane == 0) *done = 0;   // stream-ordered reset for k_tail

  const int pr0  = chk * 256;
  const int nval = min(256, P_ - pr0);
  sbox[lane] = boxes[img * NOBJ_ * 4 + lane];
  if (lane < NOBJ_) slab[lane] = labels[img * NOBJ_ + lane];

  const size_t brow = (size_t)img * P_ + pr0;
  const float4* g4 = reinterpret_cast<const float4*>(scores + brow * (size_t)C_);
  // clamp index so the very last block never reads past the scores buffer
  const int lim = (int)(((size_t)B_ * P_ - brow) * C_ / 4) - 1;

  auto STAGE = [&](int t, float* dst){
    const int b4 = t * TILE_F4;
    #pragma unroll
    for (int k = 0; k < 5; ++k){
      int idx = min(b4 + k * 64 + lane, lim);
      __builtin_amdgcn_global_load_lds(
          (const __attribute__((address_space(1))) void*)(g4 + idx),
          (__attribute__((address_space(3))) void*)(dst + k * 256), 16, 0, 0);
    }
    int idx = min(b4 + 320 + lane, lim);
    if (lane < 4)
      __builtin_amdgcn_global_load_lds(
          (const __attribute__((address_space(1))) void*)(g4 + idx),
          (__attribute__((address_space(3))) void*)(dst + 1280), 16, 0, 0);
  };

  STAGE(0, sM);   // tile 0 flies under the IoU phase

  // ---- IoU: lane owns priors pr0 + j*64 + lane ----
  float4 prv[4]; bool pvd[4];
  #pragma unroll
  for (int j = 0; j < 4; ++j){
    int idx = j * 64 + lane;
    pvd[j] = idx < nval;
    prv[j] = reinterpret_cast<const float4*>(priors)[pr0 + (pvd[j] ? idx : 0)];
  }
  float px0[4], py0[4], px1[4], py1[4], pa[4];
  #pragma unroll
  for (int j = 0; j < 4; ++j){
    px0[j] = prv[j].x - prv[j].z * 0.5f;  py0[j] = prv[j].y - prv[j].w * 0.5f;
    px1[j] = prv[j].x + prv[j].z * 0.5f;  py1[j] = prv[j].y + prv[j].w * 0.5f;
    pa[j]  = (px1[j] - px0[j]) * (py1[j] - py0[j]);
  }
  float mx[4]; int am[4];
  #pragma unroll
  for (int j = 0; j < 4; ++j){ mx[j] = -1.f; am[j] = 0; }

  #pragma unroll
  for (int o = 0; o < NOBJ_; ++o){
    float bx0 = sbox[o*4+0], by0 = sbox[o*4+1], bx1 = sbox[o*4+2], by1 = sbox[o*4+3];
    float ba = (bx1 - bx0) * (by1 - by0);
    float bbv = -1.f; int bbi = 0x7FFFFFFF;
    #pragma unroll
    for (int j = 0; j < 4; ++j){
      float v = iou_pb(bx0, by0, bx1, by1, ba, px0[j], py0[j], px1[j], py1[j], pa[j]);
      if (!pvd[j]) v = -2.f;
      int p = pr0 + j * 64 + lane;
      if (v > bbv){ bbv = v; bbi = p; }          // j asc => first-wins
      if (v > mx[j]){ mx[j] = v; am[j] = o; }    // o asc => first-wins
    }
    #pragma unroll
    for (int off = 32; off; off >>= 1){
      float v2 = __shfl_down(bbv, off);
      int   i2 = __shfl_down(bbi, off);
      if (v2 > bbv || (v2 == bbv && i2 < bbi)){ bbv = v2; bbi = i2; }
    }
    if (lane == 0)
      pob[(size_t)blkid * NOBJ_ + o] =
          ((u64)__float_as_uint(bbv) << 32) | (u64)(0xFFFFFFFFu - (unsigned)bbi);
  }
  #pragma unroll
  for (int j = 0; j < 4; ++j){ lmx[j*64 + lane] = mx[j]; lam[j*64 + lane] = am[j]; }

  // ---- CE: 16 tiles x 16 rows, 4 lanes per row ----
  int cnt = 0; float sl1 = 0.f, cpos = 0.f;
  const int rr = lane & 15, h = lane >> 4;
  const int rbase = rr * 81 + (h == 0 ? 0 : 1 + 20 * h);   // h0:21, h1-3:20 elems

  auto COMPUTE = [&](int t){
    const float* lb = sM + (t & 1) * TILE_F;
    float sa = 0.f, sb = 0.f;
    #pragma unroll
    for (int j = 0; j < 10; ++j){
      sa += __expf(lb[rbase + 2*j]);
      sb += __expf(lb[rbase + 2*j + 1]);
    }
    if (h == 0) sa += __expf(lb[rbase + 20]);
    float sum = sa + sb;
    sum += __shfl_xor(sum, 16);
    sum += __shfl_xor(sum, 32);
    if (h == 0){
      int pl_ = t * 16 + rr;
      if (pl_ < nval){
        size_t row = brow + pl_;
        float lse = __logf(sum);
        float s0  = lb[rr * 81];
        bool pos = lmx[pl_] >= 0.5f;
        ce_neg[row] = pos ? 0.f : fmaxf(lse - s0, 0.f);
        if (pos){
          int a = lam[pl_];
          int lb2 = slab[a];
          cpos += lse - lb[rr * 81 + lb2];
          ++cnt;
          float4 pr  = reinterpret_cast<const float4*>(priors)[pr0 + pl_];
          float4 pl4 = reinterpret_cast<const float4*>(pred_locs)[row];
          sl1 += sl1_row4(sbox, a, pr, pl4);
        }
      }
    }
  };

  for (int t = 0; t < 15; ++t){
    STAGE(t + 1, sM + ((t + 1) & 1) * TILE_F);
    asm volatile("s_waitcnt vmcnt(6)" ::: "memory");   // tile t ready; t+1 flying
    COMPUTE(t);
  }
  asm volatile("s_waitcnt vmcnt(0)" ::: "memory");
  COMPUTE(15);

  #pragma unroll
  for (int off = 8; off; off >>= 1){
    cnt  += __shfl_down(cnt, off);
    sl1  += __shfl_down(sl1, off);
    cpos += __shfl_down(cpos, off);
  }
  if (lane == 0){
    npos_c[blkid] = cnt; sl1_c[blkid] = sl1; cpos_c[blkid] = cpos;
  }
}

// ---------------- k_tail: forced-match corrections + top-K + final ----------
// grid 64 x 1024. One block per image.
__global__ __launch_bounds__(1024) void k_tail(const float* __restrict__ scores,
                                               const float* __restrict__ priors,
                                               const float* __restrict__ boxes,
                                               const int*   __restrict__ labels,
                                               const float* __restrict__ pred_locs,
                                               const u64*   __restrict__ pob,
                                               const int*   __restrict__ npos_c,
                                               const float* __restrict__ sl1_c,
                                               const float* __restrict__ cpos_c,
                                               float* __restrict__ ce_neg,
                                               int*   __restrict__ npos_img,
                                               float* __restrict__ sl1_img,
                                               float* __restrict__ cpos_img,
                                               float* __restrict__ hard_img,
                                               int*   __restrict__ done,
                                               float* __restrict__ out){
  const int img = blockIdx.x, tid = threadIdx.x;
  const int lane = tid & 63, wid = tid >> 6;
  __shared__ u64   pm[64][NOBJ_];
  __shared__ int   sppo[NOBJ_];
  __shared__ float sbox[NOBJ_ * 4];
  __shared__ int   slab[NOBJ_];
  __shared__ float sredA[96], sredB[96];
  __shared__ int   sredI[96];
  __shared__ int   s_npos;
  __shared__ float s_sl1, s_cpos, s_hard;
  __shared__ int   s_last;

  if (tid < 64) sbox[tid] = boxes[img * 64 + tid];
  if (tid < 16) slab[tid] = labels[img * 16 + tid];
  {
    int o = tid & 15, g = tid >> 4;    // g in [0,64)
    u64 m = pob[(size_t)(img * CHUNKS_ + g) * NOBJ_ + o];
    if (g < 32){
      u64 e = pob[(size_t)(img * CHUNKS_ + 64 + g) * NOBJ_ + o];
      if (e > m) m = e;
    }
    pm[g][o] = m;
  }
  if (tid < 96){
    sredI[tid] = npos_c[img * CHUNKS_ + tid];
    sredA[tid] = sl1_c[img * CHUNKS_ + tid];
    sredB[tid] = cpos_c[img * CHUNKS_ + tid];
  }
  __syncthreads();
  if (tid < 16){
    u64 m = pm[0][tid];
    for (int g = 1; g < 64; ++g) if (pm[g][tid] > m) m = pm[g][tid];
    sppo[tid] = (int)(0xFFFFFFFFu - (unsigned)(m & 0xFFFFFFFFull));
  }
  if (tid == 0){
    int c = 0; float s = 0.f, q = 0.f;
    for (int i = 0; i < 96; ++i){ c += sredI[i]; s += sredA[i]; q += sredB[i]; }
    s_npos = c; s_sl1 = s; s_cpos = q;
  }
  __syncthreads();

  // corrections: lanes 0..15 of wave 0 handle the <=16 forced priors
  int npd = 0; float sld = 0.f, cpd = 0.f;
  if (wid == 0 && lane < 16){
    int o = lane, p = sppo[o];
    bool is_last = true;
    for (int o2 = o + 1; o2 < 16; ++o2) if (sppo[o2] == p) is_last = false;
    if (is_last){
      float4 pr = reinterpret_cast<const float4*>(priors)[p];
      float px0 = pr.x - pr.z * 0.5f, py0 = pr.y - pr.w * 0.5f;
      float px1 = pr.x + pr.z * 0.5f, py1 = pr.y + pr.w * 0.5f;
      float pa  = (px1 - px0) * (py1 - py0);
      float mxo = -1.f; int amo = 0;
      for (int oo = 0; oo < 16; ++oo){
        float bx0 = sbox[oo*4+0], by0 = sbox[oo*4+1],
              bx1 = sbox[oo*4+2], by1 = sbox[oo*4+3];
        float ba = (bx1 - bx0) * (by1 - by0);
        float v = iou_pb(bx0, by0, bx1, by1, ba, px0, py0, px1, py1, pa);
        if (v > mxo){ mxo = v; amo = oo; }
      }
      bool pos_old = mxo >= 0.5f;
      size_t row = (size_t)img * P_ + p;
      float4 pl4 = reinterpret_cast<const float4*>(pred_locs)[row];
      float sl_new = sl1_row4(sbox, o, pr, pl4);
      int lab_new = slab[o];
      float s_new = scores[row * (size_t)C_ + lab_new];
      if (pos_old){
        float sl_old = sl1_row4(sbox, amo, pr, pl4);
        float s_old  = scores[row * (size_t)C_ + slab[amo]];
        sld = sl_new - sl_old;
        cpd = s_old - s_new;               // lse cancels
      } else {
        npd = 1;
        float ce0v = ce_neg[row];          // = lse - s0 (>=0 up to rounding)
        float s0   = scores[row * (size_t)C_];
        sld = sl_new;
        cpd = ce0v + s0 - s_new;
        ce_neg[row] = 0.f;                 // now positive: excluded from topk
      }
    }
  }
  if (wid == 0){
    #pragma unroll
    for (int off = 8; off; off >>= 1){
      npd += __shfl_down(npd, off);
      sld += __shfl_down(sld, off);
      cpd += __shfl_down(cpd, off);
    }
    if (lane == 0){
      s_npos += npd; s_sl1 += sld; s_cpos += cpd;
      npos_img[img] = s_npos; sl1_img[img] = s_sl1; cpos_img[img] = s_cpos;
    }
  }
  __threadfence();
  __syncthreads();

  // ---- per-image exact top-K sum (radix select over f32 bits) ----
  const int K = 3 * s_npos;
  const float* v = ce_neg + (size_t)img * P_;
  __shared__ int hist[32 * 257];
  __shared__ int histT[256];
  __shared__ unsigned s_prefix;
  __shared__ int s_rem;
  __shared__ float rsum[16];
  const int copy = tid & 31;

  if (K <= 0){
    if (tid == 0) s_hard = 0.f;
    __syncthreads();
  } else if (K >= P_){
    float s = 0.f;
    for (int p = tid; p < P_; p += 1024) s += v[p];
    #pragma unroll
    for (int off = 32; off; off >>= 1) s += __shfl_down(s, off);
    if (lane == 0) rsum[wid] = s;
    __syncthreads();
    if (tid == 0){
      float t = 0.f;
      for (int w = 0; w < 16; ++w) t += rsum[w];
      s_hard = t;
    }
    __syncthreads();
  } else {
    unsigned prefix = 0; int remaining = K;
    for (int shift = 24; shift >= 0; shift -= 8){
      for (int i = tid; i < 32 * 257; i += 1024) hist[i] = 0;
      __syncthreads();
      unsigned hmask = (shift == 24) ? 0u : (0xFFFFFFFFu << (shift + 8));
      for (int p = tid; p < P_; p += 1024){
        unsigned u = __float_as_uint(v[p]);
        if ((u & hmask) == prefix) atomicAdd(&hist[copy * 257 + ((u >> shift) & 255)], 1);
      }
      __syncthreads();
      if (tid < 256){
        int s = 0;
        #pragma unroll
        for (int w = 0; w < 32; ++w) s += hist[w * 257 + tid];
        histT[tid] = s;
      }
      __syncthreads();
      if (wid == 0){
        int a0 = histT[lane*4+0], a1 = histT[lane*4+1],
            a2 = histT[lane*4+2], a3 = histT[lane*4+3];
        int tl = a0 + a1 + a2 + a3;
        int run = tl;
        #pragma unroll
        for (int off = 1; off < 64; off <<= 1){
          int x = __shfl_down(run, off);
          if (lane + off < 64) run += x;
        }
        int E  = run - tl;
        int s3 = E;
        int s2 = s3 + a3;
        int s1 = s2 + a2;
        int s0 = s1 + a1;
        if (s0 < remaining && s0 + a0 >= remaining){ s_prefix = prefix | ((unsigned)(lane*4+0) << shift); s_rem = remaining - s0; }
        if (s1 < remaining && s1 + a1 >= remaining){ s_prefix = prefix | ((unsigned)(lane*4+1) << shift); s_rem = remaining - s1; }
        if (s2 < remaining && s2 + a2 >= remaining){ s_prefix = prefix | ((unsigned)(lane*4+2) << shift); s_rem = remaining - s2; }
        if (s3 < remaining && s3 + a3 >= remaining){ s_prefix = prefix | ((unsigned)(lane*4+3) << shift); s_rem = remaining - s3; }
      }
      __syncthreads();
      prefix = s_prefix;
      remaining = s_rem;
      __syncthreads();
    }
    float tv = __uint_as_float(prefix);
    float sgt = 0.f;
    for (int p = tid; p < P_; p += 1024){
      unsigned u = __float_as_uint(v[p]);
      if (u > prefix) sgt += v[p];
    }
    #pragma unroll
    for (int off = 32; off; off >>= 1) sgt += __shfl_down(sgt, off);
    if (lane == 0) rsum[wid] = sgt;
    __syncthreads();
    if (tid == 0){
      float s = 0.f;
      for (int w = 0; w < 16; ++w) s += rsum[w];
      s_hard = s + (float)remaining * tv;
    }
    __syncthreads();
  }

  // ---- fused final combine (last block) ----
  if (tid == 0){
    hard_img[img] = s_hard;
    __threadfence();
    int old = atomicAdd(done, 1);
    s_last = (old == B_ - 1) ? 1 : 0;
  }
  __syncthreads();
  if (s_last){
    if (tid == 0) __threadfence();   // acquire: order gather loads after done RMW
    __syncthreads();
    float np = 0.f, sl = 0.f, cp = 0.f, hd = 0.f;
    if (tid < 64){
      np = (float)__hip_atomic_load(&npos_img[tid], __ATOMIC_RELAXED, __HIP_MEMORY_SCOPE_AGENT);
      sl = __hip_atomic_load(&sl1_img[tid],  __ATOMIC_RELAXED, __HIP_MEMORY_SCOPE_AGENT);
      cp = __hip_atomic_load(&cpos_img[tid], __ATOMIC_RELAXED, __HIP_MEMORY_SCOPE_AGENT);
      hd = __hip_atomic_load(&hard_img[tid], __ATOMIC_RELAXED, __HIP_MEMORY_SCOPE_AGENT);
    }
    if (wid == 0){
      #pragma unroll
      for (int off = 32; off; off >>= 1){
        np += __shfl_down(np, off);
        sl += __shfl_down(sl, off);
        cp += __shfl_down(cp, off);
        hd += __shfl_down(hd, off);
      }
      if (lane == 0){
        out[0] = (hd + cp) / np + sl / (np * 4.0f);
      }
    }
  }
}

extern "C" void kernel_launch(void* const* d_in, const int* in_sizes, int n_in,
                              void* d_out, int out_size, void* d_ws, size_t ws_size,
                              hipStream_t stream){
  const float* pred_locs = (const float*)d_in[0];
  const float* scores    = (const float*)d_in[1];
  const float* boxes     = (const float*)d_in[2];
  const int*   labels    = (const int*)d_in[3];
  const float* priors    = (const float*)d_in[4];

  const size_t BP = (size_t)B_ * P_;
  char* w = (char*)d_ws;
  float* ce_neg = (float*)w;                                   // BP f32
  u64*   pob    = (u64*)(w + BP * 4);                          // NBLK_*16 u64
  char*  w2 = w + BP * 4 + (size_t)NBLK_ * NOBJ_ * 8;
  int*   npos_c = (int*)  w2;                                  // NBLK_
  float* sl1_c  = (float*)(w2 + NBLK_ * 4);                    // NBLK_
  float* cpos_c = (float*)(w2 + NBLK_ * 8);                    // NBLK_
  char*  w3 = w2 + NBLK_ * 12;
  int*   npos_img = (int*)  w3;                                // 64
  float* sl1_img  = (float*)(w3 + 256);
  float* cpos_img = (float*)(w3 + 512);
  float* hard_img = (float*)(w3 + 768);
  int*   done     = (int*)  (w3 + 1024);

  dim3 g1(CHUNKS_, B_);
  k_main<<<g1, 64, 0, stream>>>(scores, priors, boxes, labels, pred_locs,
                                ce_neg, pob, npos_c, sl1_c, cpos_c, done);

  k_tail<<<B_, 1024, 0, stream>>>(scores, priors, boxes, labels, pred_locs,
                                  pob, npos_c, sl1_c, cpos_c, ce_neg,
                                  npos_img, sl1_img, cpos_img, hard_img,
                                  done, (float*)d_out);
}